// Round 7
// baseline (251.330 us; speedup 1.0000x reference)
//
#include <hip/hip_runtime.h>
#include <math.h>

// LineFinderLoss: B=384 independent exact LSAs (L x 256, L<=64) + loss.
// One wave per batch; each lane owns 4 pred columns (j = lane + 64k).
// Round 7:
//  - LAPJV Augmenting Row Reduction (2 passes) before SSP: each free row
//    grabs its argmin column (displacing the owner) and pays the bid gap
//    into v[j1]. Kills the degenerate ~L^2/2 pop count caused by the
//    column-constant confidence term. Duals stay feasible (v only
//    decreases, only on displaced columns), matched edges stay tight ->
//    SSP from this state is exact (same unique optimum).
//  - Fused finalization: per-block partials via device-scope f64 atomicAdd
//    + ticket counter; last block writes out[0..3]. No second kernel.
//  - LDS shrinks to the 3x64 label arrays (epilogue gather only).

#define B_ 384
#define N_ 256
#define M_ 64

typedef unsigned long long u64;

static __device__ __forceinline__ double mkdbl(int lo, int hi) {
  return __longlong_as_double(((long long)hi << 32) | (unsigned int)lo);
}
static __device__ __forceinline__ int lo32d(double d) {
  return (int)__double_as_longlong(d);
}
static __device__ __forceinline__ int hi32d(double d) {
  return (int)(__double_as_longlong(d) >> 32);
}
static __device__ __forceinline__ float readlane_f32(float x, int l) {
  return __int_as_float(__builtin_amdgcn_readlane(__float_as_int(x), l));
}
static __device__ __forceinline__ double readlane_f64(double x, int l) {
  int lo = __builtin_amdgcn_readlane(lo32d(x), l);
  int hi = __builtin_amdgcn_readlane(hi32d(x), l);
  return mkdbl(lo, hi);
}

// fp32 cost with numpy's exact association order:
// C = ((0.1f*nd)*0.5f - lc) + lca, nd = (d0*d0 + d1*d1) + d2*d2
static __device__ __forceinline__ float costf(float px, float py, float pz,
                                              float lc, float lca,
                                              float lx, float ly, float lz) {
  const float d0 = __fsub_rn(px, lx);
  const float d1 = __fsub_rn(py, ly);
  const float d2 = __fsub_rn(pz, lz);
  const float nd = __fadd_rn(__fadd_rn(__fmul_rn(d0, d0), __fmul_rn(d1, d1)),
                             __fmul_rn(d2, d2));
  return __fadd_rn(__fsub_rn(__fmul_rn(__fmul_rn(0.1f, nd), 0.5f), lc), lca);
}

// f64 min-reduce step via DPP (keys finite, >= 0, payload in low byte).
#define DPP_MIN_F64(CTRL, RMASK)                                               \
  {                                                                            \
    int nlo = __builtin_amdgcn_update_dpp(-1, lo32d(ck), CTRL, RMASK, 0xF, false);         \
    int nhi = __builtin_amdgcn_update_dpp(0x7FEFFFFF, hi32d(ck), CTRL, RMASK, 0xF, false); \
    ck = fmin(ck, mkdbl(nlo, nhi));                                            \
  }

// (min, second-min) pair reduce step. The shr1/2/4/8 + bcast15/31 pattern
// merges DISJOINT lane sets at every step, so no value is double-counted.
#define DPP_MIN2_F64(CTRL, RMASK)                                              \
  {                                                                            \
    int n1lo = __builtin_amdgcn_update_dpp(-1, lo32d(m1), CTRL, RMASK, 0xF, false);         \
    int n1hi = __builtin_amdgcn_update_dpp(0x7FEFFFFF, hi32d(m1), CTRL, RMASK, 0xF, false); \
    int n2lo = __builtin_amdgcn_update_dpp(-1, lo32d(m2), CTRL, RMASK, 0xF, false);         \
    int n2hi = __builtin_amdgcn_update_dpp(0x7FEFFFFF, hi32d(m2), CTRL, RMASK, 0xF, false); \
    double n1 = mkdbl(n1lo, n1hi), n2 = mkdbl(n2lo, n2hi);                     \
    double hi12 = fmax(m1, n1);                                                \
    m1 = fmin(m1, n1);                                                         \
    m2 = fmin(fmin(m2, n2), hi12);                                             \
  }

__global__ __launch_bounds__(64) void lsa_loss_kernel(
    const float* __restrict__ pred,
    const float* __restrict__ label,
    const int* __restrict__ label_len,
    double* __restrict__ ws,
    float* __restrict__ out)
{
  const int b = blockIdx.x;
  const int lane = threadIdx.x;  // 0..63

  __shared__ float lab_x[M_], lab_y[M_], lab_z[M_];

  const float* lp = label + (size_t)(b * M_ + lane) * 3;
  const float labx = lp[0], laby = lp[1], labz = lp[2];
  lab_x[lane] = labx; lab_y[lane] = laby; lab_z[lane] = labz;

  float px[4], py[4], pz[4], lc[4], lca[4];
  double v[4];
  const float4* pred4 = reinterpret_cast<const float4*>(pred);
#pragma unroll
  for (int k = 0; k < 4; ++k) {
    const float4 p = pred4[b * N_ + lane + 64 * k];
    px[k] = p.x; py[k] = p.y; pz[k] = p.z;
    lc[k]  = logf(__fadd_rn(p.w, 1e-5f));
    lca[k] = logf(__fadd_rn(__fsub_rn(1.0f, p.w), 1e-5f));
    v[k] = 0.0;
  }
  int rfc[4] = {-1, -1, -1, -1};  // row4col, distributed (col j=lane+64k)
  int c4r = -1;                   // col4row[lane]
  double u_reg = 0.0;             // u[lane]

  int L = label_len[b];
  L = (L < 1) ? 1 : ((L > M_) ? M_ : L);

  __syncthreads();  // label LDS visible (epilogue gather)

  const double INF = (double)INFINITY;

  // ---- Augmenting Row Reduction, 2 passes (LAPJV-style, exactness-safe) ----
  u64 pend = (L >= 64) ? ~0ull : ((1ull << L) - 1ull);
  for (int pass = 0; pass < 2; ++pass) {
    u64 next = 0ull;
    while (pend) {
      const int r = (int)__builtin_ctzll(pend);
      pend &= pend - 1ull;
      const float lx = readlane_f32(labx, r);
      const float ly = readlane_f32(laby, r);
      const float lz = readlane_f32(labz, r);
      double cand[4];
#pragma unroll
      for (int k = 0; k < 4; ++k) {
        const int j = lane + 64 * k;
        const float cf = costf(px[k], py[k], pz[k], lc[k], lca[k], lx, ly, lz);
        // reduced cost + 16 > 0 always (C >= -11.52, v <= 0) -> normal f64,
        // low-byte payload packing stays order-correct.
        const double dd = ((double)cf - v[k]) + 16.0;
        const int klo = (lo32d(dd) & ~0xFF) | j;
        cand[k] = mkdbl(klo, hi32d(dd));
      }
      const double a    = fmin(cand[0], cand[1]);
      const double abig = fmax(cand[0], cand[1]);
      const double c    = fmin(cand[2], cand[3]);
      const double cbig = fmax(cand[2], cand[3]);
      double m1 = fmin(a, c);
      double m2 = fmin(fmax(a, c), fmin(abig, cbig));
      DPP_MIN2_F64(0x111, 0xF);  // row_shr:1
      DPP_MIN2_F64(0x112, 0xF);  // row_shr:2
      DPP_MIN2_F64(0x114, 0xF);  // row_shr:4
      DPP_MIN2_F64(0x118, 0xF);  // row_shr:8
      DPP_MIN2_F64(0x142, 0xA);  // row_bcast:15 -> rows 1,3
      DPP_MIN2_F64(0x143, 0xC);  // row_bcast:31 -> rows 2,3
      const int w1lo = __builtin_amdgcn_readlane(lo32d(m1), 63);
      const int w1hi = __builtin_amdgcn_readlane(hi32d(m1), 63);
      const int w2lo = __builtin_amdgcn_readlane(lo32d(m2), 63);
      const int w2hi = __builtin_amdgcn_readlane(hi32d(m2), 63);
      const int j1 = w1lo & 0xFF;
      const double d1 = mkdbl(w1lo & ~0xFF, w1hi);
      const double d2 = mkdbl(w2lo & ~0xFF, w2hi);
      if (lane == r) u_reg = d2 - 16.0;
      const double vdec = d2 - d1;  // >= 0
      const int kk1 = j1 >> 6;
      const bool selfc = (lane == (j1 & 63));
      v[0] -= (selfc && kk1 == 0) ? vdec : 0.0;
      v[1] -= (selfc && kk1 == 1) ? vdec : 0.0;
      v[2] -= (selfc && kk1 == 2) ? vdec : 0.0;
      v[3] -= (selfc && kk1 == 3) ? vdec : 0.0;
      const int lsel = j1 & 63;
      const int r0 = __builtin_amdgcn_readlane(rfc[0], lsel);
      const int r1 = __builtin_amdgcn_readlane(rfc[1], lsel);
      const int r2 = __builtin_amdgcn_readlane(rfc[2], lsel);
      const int r3 = __builtin_amdgcn_readlane(rfc[3], lsel);
      const int kold = (kk1 == 0) ? r0 : (kk1 == 1) ? r1 : (kk1 == 2) ? r2 : r3;
      rfc[0] = (selfc && kk1 == 0) ? r : rfc[0];
      rfc[1] = (selfc && kk1 == 1) ? r : rfc[1];
      rfc[2] = (selfc && kk1 == 2) ? r : rfc[2];
      rfc[3] = (selfc && kk1 == 3) ? r : rfc[3];
      if (lane == r) c4r = j1;
      if (kold >= 0) next |= (1ull << kold);  // displaced -> next pass
    }
    pend = next;
  }
  u64 free_mask = pend;

  // ---- SSP for the remaining free rows (exact, register-resident, R6) ----
  while (free_mask) {
    const int cur_row = (int)__builtin_ctzll(free_mask);
    free_mask &= free_mask - 1;

    double shk[4] = {INF, INF, INF, INF};
    int pv[4] = {0, 0, 0, 0};
    int schi[4] = {0, 0, 0, 0};
    double mv_join = 0.0;
    int joined = 0;
    double min_val = 0.0;
    int i_cur = cur_row;
    double u_i = readlane_f64(u_reg, i_cur);
    float lx = readlane_f32(labx, i_cur);
    float ly = readlane_f32(laby, i_cur);
    float lz = readlane_f32(labz, i_cur);
    double t = 0.0 - u_i;
    int sink = -1;

    while (true) {
      double tv[4];
#pragma unroll
      for (int k = 0; k < 4; ++k) tv[k] = t - v[k];

      double cand[4];
#pragma unroll
      for (int k = 0; k < 4; ++k) {
        const int j = lane + 64 * k;
        const float cf = costf(px[k], py[k], pz[k], lc[k], lca[k], lx, ly, lz);
        double dd = (double)cf + tv[k];
        dd = fmax(dd, 0.0);
        const int klo = (lo32d(dd) & ~0xFF) | j;
        const int khi = hi32d(dd);
        const int khi_m = schi[k] ? 0x7FEFFFFF : khi;
        const double ckey = mkdbl(klo, khi_m);
        const bool upd = ckey < shk[k];
        shk[k] = upd ? ckey : shk[k];
        pv[k]  = upd ? i_cur : pv[k];
        cand[k] = ckey;
      }
      const double m01 = fmin(cand[0], cand[1]);
      const double m23 = fmin(cand[2], cand[3]);
      double ck = fmin(m01, m23);
      DPP_MIN_F64(0x111, 0xF);
      DPP_MIN_F64(0x112, 0xF);
      DPP_MIN_F64(0x114, 0xF);
      DPP_MIN_F64(0x118, 0xF);
      DPP_MIN_F64(0x142, 0xA);
      DPP_MIN_F64(0x143, 0xC);
      const int wlo = __builtin_amdgcn_readlane(lo32d(ck), 63);
      const int whi = __builtin_amdgcn_readlane(hi32d(ck), 63);
      const int j_min = wlo & 0xFF;
      min_val = mkdbl(wlo & ~0xFF, whi);
      const int kk = j_min >> 6;
      const int hit = (lane == (j_min & 63)) ? 1 : 0;
      schi[0] |= hit & (int)(kk == 0);
      schi[1] |= hit & (int)(kk == 1);
      schi[2] |= hit & (int)(kk == 2);
      schi[3] |= hit & (int)(kk == 3);
      const int lsel = j_min & 63;
      const int r0 = __builtin_amdgcn_readlane(rfc[0], lsel);
      const int r1 = __builtin_amdgcn_readlane(rfc[1], lsel);
      const int r2 = __builtin_amdgcn_readlane(rfc[2], lsel);
      const int r3 = __builtin_amdgcn_readlane(rfc[3], lsel);
      const int r4 = (kk == 0) ? r0 : (kk == 1) ? r1 : (kk == 2) ? r2 : r3;
      if (r4 < 0) { sink = j_min; break; }
      i_cur = r4;
      if (lane == i_cur) { mv_join = min_val; joined = 1; }
      u_i = readlane_f64(u_reg, i_cur);
      lx = readlane_f32(labx, i_cur);
      ly = readlane_f32(laby, i_cur);
      lz = readlane_f32(labz, i_cur);
      t = min_val - u_i;
    }

    if (lane == cur_row)  u_reg += min_val;
    else if (joined)      u_reg += min_val - mv_join;
#pragma unroll
    for (int k = 0; k < 4; ++k) {
      if (schi[k]) {
        const double shd = mkdbl(lo32d(shk[k]) & ~0xFF, hi32d(shk[k]));
        v[k] -= (min_val - shd);
      }
    }

    {
      int j = sink;
      while (true) {
        const int kkj = j >> 6, lj = j & 63;
        const int p0 = __builtin_amdgcn_readlane(pv[0], lj);
        const int p1 = __builtin_amdgcn_readlane(pv[1], lj);
        const int p2 = __builtin_amdgcn_readlane(pv[2], lj);
        const int p3 = __builtin_amdgcn_readlane(pv[3], lj);
        const int ii = (kkj == 0) ? p0 : (kkj == 1) ? p1 : (kkj == 2) ? p2 : p3;
        const bool self = (lane == lj);
        rfc[0] = (self && kkj == 0) ? ii : rfc[0];
        rfc[1] = (self && kkj == 1) ? ii : rfc[1];
        rfc[2] = (self && kkj == 2) ? ii : rfc[2];
        rfc[3] = (self && kkj == 3) ? ii : rfc[3];
        const int jn = __builtin_amdgcn_readlane(c4r, ii);
        if (lane == ii) c4r = j;
        if (ii == cur_row) break;
        j = jn;
      }
    }
  }

  // ---- Loss partials ----
  double loc = 0.0, cpos = 0.0, cneg = 0.0;
#pragma unroll
  for (int k = 0; k < 4; ++k) {
    const int l = rfc[k];
    if (l >= 0) {
      const float d0 = __fsub_rn(px[k], lab_x[l]);
      const float d1 = __fsub_rn(py[k], lab_y[l]);
      const float d2 = __fsub_rn(pz[k], lab_z[l]);
      const float nd = __fadd_rn(__fadd_rn(__fmul_rn(d0, d0), __fmul_rn(d1, d1)),
                                 __fmul_rn(d2, d2));
      loc += (double)nd;
      cpos -= (double)lc[k];
    } else {
      cneg -= (double)lca[k];
    }
  }
  for (int off = 32; off >= 1; off >>= 1) {
    loc += __shfl_xor(loc, off, 64);
    cpos += __shfl_xor(cpos, off, 64);
    cneg += __shfl_xor(cneg, off, 64);
  }

  // ---- Fused finalization: all cross-block data moves via device atomics ----
  // ws[0]=Σ loc, ws[1]=Σ (cpos+cneg+1e-4), ws[2]=cpos[B-1], ws[3]=cneg[B-1],
  // counter at ((uint*)ws)[8]. Zeroed by hipMemsetAsync in kernel_launch.
  if (lane == 0) {
    atomicAdd(&ws[0], loc);
    atomicAdd(&ws[1], cpos + cneg + 1e-4);
    if (b == B_ - 1) { atomicAdd(&ws[2], cpos); atomicAdd(&ws[3], cneg); }
    __threadfence();
    unsigned int* cnt = (unsigned int*)(ws + 4);
    const unsigned int old = atomicAdd(cnt, 1u);
    if (old == (unsigned int)(B_ - 1)) {
      __threadfence();
      const double loc_t  = atomicAdd(&ws[0], 0.0);  // atomic read (coherent)
      const double conf_t = atomicAdd(&ws[1], 0.0);
      const double cpos_l = atomicAdd(&ws[2], 0.0);
      const double cneg_l = atomicAdd(&ws[3], 0.0);
      const double lloc = 0.1 * (loc_t * 0.5);  // ALPHA * location_loss
      out[0] = (float)(lloc + conf_t);
      out[1] = (float)lloc;
      out[2] = (float)cpos_l;
      out[3] = (float)cneg_l;
    }
  }
}

extern "C" void kernel_launch(void* const* d_in, const int* in_sizes, int n_in,
                              void* d_out, int out_size, void* d_ws, size_t ws_size,
                              hipStream_t stream) {
  const float* pred = (const float*)d_in[0];       // (B, N, 4) fp32
  const float* label = (const float*)d_in[1];      // (B, M, 3) fp32
  const int* label_len = (const int*)d_in[2];      // (B,) int32
  double* ws = (double*)d_ws;
  float* out = (float*)d_out;

  // Zero the 4 accumulators + ticket counter (ws is poisoned 0xAA each call).
  hipMemsetAsync(d_ws, 0, 64, stream);
  lsa_loss_kernel<<<B_, 64, 0, stream>>>(pred, label, label_len, ws, out);
}

// Round 8
// 206.591 us; speedup vs baseline: 1.2166x; 1.2166x over previous
//
#include <hip/hip_runtime.h>
#include <math.h>

// LineFinderLoss: B=384 independent exact LSAs (L x 256, L<=64) + loss.
// One wave per batch; each lane owns 4 pred columns (j = lane + 64k).
// Round 8: R6 register-resident JV (ARR reverted — it was an eps=0 auction,
// no pop reduction, +28% time) with row4col carried in the argmin key:
//   key = (bits(d) & ~0x7FFF) | (j << 7) | (row4col[j] + 1)
// so the popped column's matched row pops out of the single v_min_f64
// reduce — removes the 4-readlane rfc lookup (~30 cy) from the ~185 cy
// serial pop chain. 15-bit truncation = 2^-37 rel (R4-proven, absmax 0).
// Fused finalization via device-scope f64 atomics + ticket (free).

#define B_ 384
#define N_ 256
#define M_ 64

typedef unsigned long long u64;
#define PAYBITS 0x7FFF

static __device__ __forceinline__ double mkdbl(int lo, int hi) {
  return __longlong_as_double(((long long)hi << 32) | (unsigned int)lo);
}
static __device__ __forceinline__ int lo32d(double d) {
  return (int)__double_as_longlong(d);
}
static __device__ __forceinline__ int hi32d(double d) {
  return (int)(__double_as_longlong(d) >> 32);
}
static __device__ __forceinline__ float readlane_f32(float x, int l) {
  return __int_as_float(__builtin_amdgcn_readlane(__float_as_int(x), l));
}
static __device__ __forceinline__ double readlane_f64(double x, int l) {
  int lo = __builtin_amdgcn_readlane(lo32d(x), l);
  int hi = __builtin_amdgcn_readlane(hi32d(x), l);
  return mkdbl(lo, hi);
}

// fp32 cost with numpy's exact association order:
// C = ((0.1f*nd)*0.5f - lc) + lca, nd = (d0*d0 + d1*d1) + d2*d2
static __device__ __forceinline__ float costf(float px, float py, float pz,
                                              float lc, float lca,
                                              float lx, float ly, float lz) {
  const float d0 = __fsub_rn(px, lx);
  const float d1 = __fsub_rn(py, ly);
  const float d2 = __fsub_rn(pz, lz);
  const float nd = __fadd_rn(__fadd_rn(__fmul_rn(d0, d0), __fmul_rn(d1, d1)),
                             __fmul_rn(d2, d2));
  return __fadd_rn(__fsub_rn(__fmul_rn(__fmul_rn(0.1f, nd), 0.5f), lc), lca);
}

// f64 min-reduce step via DPP (keys finite, >= 0, payload in low 15 bits).
// Lanes without a source get max-finite-double (lo=-1, hi=0x7FEFFFFF).
#define DPP_MIN_F64(CTRL, RMASK)                                               \
  {                                                                            \
    int nlo = __builtin_amdgcn_update_dpp(-1, lo32d(ck), CTRL, RMASK, 0xF, false);         \
    int nhi = __builtin_amdgcn_update_dpp(0x7FEFFFFF, hi32d(ck), CTRL, RMASK, 0xF, false); \
    ck = fmin(ck, mkdbl(nlo, nhi));                                            \
  }

__global__ __launch_bounds__(64) void lsa_loss_kernel(
    const float* __restrict__ pred,
    const float* __restrict__ label,
    const int* __restrict__ label_len,
    double* __restrict__ ws,
    float* __restrict__ out)
{
  const int b = blockIdx.x;
  const int lane = threadIdx.x;  // 0..63

  __shared__ float lab_x[M_], lab_y[M_], lab_z[M_];
  __shared__ int claim[1];

  const float* lp = label + (size_t)(b * M_ + lane) * 3;
  const float labx = lp[0], laby = lp[1], labz = lp[2];
  lab_x[lane] = labx; lab_y[lane] = laby; lab_z[lane] = labz;
  if (lane == 0) claim[0] = 0x7FFFFFFF;

  float px[4], py[4], pz[4], lc[4], lca[4];
  double v[4];
  const float4* pred4 = reinterpret_cast<const float4*>(pred);
#pragma unroll
  for (int k = 0; k < 4; ++k) {
    const float4 p = pred4[b * N_ + lane + 64 * k];
    px[k] = p.x; py[k] = p.y; pz[k] = p.z;
    lc[k]  = logf(__fadd_rn(p.w, 1e-5f));
    lca[k] = logf(__fadd_rn(__fsub_rn(1.0f, p.w), 1e-5f));
    v[k] = 0.0;
  }
  int rfc[4] = {-1, -1, -1, -1};  // row4col, distributed (col j=lane+64k)
  int c4r = -1;                   // col4row[lane]

  int L = label_len[b];
  L = (L < 1) ? 1 : ((L > M_) ? M_ : L);

  __syncthreads();  // labels + claim visible

  // ---- Warm start: u_i = min_j C_ij (row reduction), v = 0 ----
  // Lane r computes row r's min over all 256 columns via key trick
  // (columns broadcast from each lane's registers would need a transpose;
  //  instead each lane-as-row scans columns from LDS-free readlane is not
  //  possible -> reuse R6's approach: row-min via per-row scan with
  //  column data broadcast lane-by-lane is O(256) readlanes; cheaper:
  //  compute per-lane candidate keys over OWN columns for each row i and
  //  min-reduce 64x? That's 64 reduces. R6 used an LDS colA copy; here we
  //  keep it simple: per-row scan with the DPP reduce, L rows total.)
  // NOTE: L <= 64 reduces of ~90 cy ≈ 6k cy one-time — negligible.
  double u_reg = 0.0;
  {
    float bestv = INFINITY;   // per-lane: row-min candidate for row r loop
    // For each row r (uniform loop), compute min_j C_rj via DPP reduce and
    // hand the result to lane r.
    for (int r = 0; r < L; ++r) {
      const float lx = readlane_f32(labx, r);
      const float ly = readlane_f32(laby, r);
      const float lz = readlane_f32(labz, r);
      double cand[4];
#pragma unroll
      for (int k = 0; k < 4; ++k) {
        const int j = lane + 64 * k;
        const float cf = costf(px[k], py[k], pz[k], lc[k], lca[k], lx, ly, lz);
        // C + 16 > 0 always (C >= -11.52) -> ordering-safe payload pack.
        const double dd = (double)cf + 16.0;
        const int klo = (lo32d(dd) & ~PAYBITS) | (j << 7);
        cand[k] = mkdbl(klo, hi32d(dd));
      }
      const double m01 = fmin(cand[0], cand[1]);
      const double m23 = fmin(cand[2], cand[3]);
      double ck = fmin(m01, m23);
      DPP_MIN_F64(0x111, 0xF);
      DPP_MIN_F64(0x112, 0xF);
      DPP_MIN_F64(0x114, 0xF);
      DPP_MIN_F64(0x118, 0xF);
      DPP_MIN_F64(0x142, 0xA);
      DPP_MIN_F64(0x143, 0xC);
      const int wlo = __builtin_amdgcn_readlane(lo32d(ck), 63);
      const int whi = __builtin_amdgcn_readlane(hi32d(ck), 63);
      const int j1 = (wlo >> 7) & 0xFF;
      // exact fp32 row-min value: recompute C(r, j1) on lane owning j1?
      // Simpler: u = truncated key value - 16 (2^-37 perturbation of u is
      // within the established tolerance; decisions use strict <).
      const double d1 = mkdbl(wlo & ~PAYBITS, whi) - 16.0;
      if (lane == r) { u_reg = d1; bestv = (float)j1; }
      (void)bestv;
      // Greedy claim: first row (smallest r) claiming j1 wins it.
      if (lane == r) {
        // do nothing here; claims resolved below via atomicMin on one slot
      }
      // Resolve greedily inline: row r takes j1 if untaken (serial loop, so
      // simple register check suffices — track taken columns in a mask).
      // Taken tracking: distributed — lane owning j1 checks rfc.
      const int kk1 = j1 >> 6;
      const bool selfc = (lane == (j1 & 63));
      int taken;
      {
        const int lsel = j1 & 63;
        const int t0 = __builtin_amdgcn_readlane(rfc[0], lsel);
        const int t1 = __builtin_amdgcn_readlane(rfc[1], lsel);
        const int t2 = __builtin_amdgcn_readlane(rfc[2], lsel);
        const int t3 = __builtin_amdgcn_readlane(rfc[3], lsel);
        taken = (kk1 == 0) ? t0 : (kk1 == 1) ? t1 : (kk1 == 2) ? t2 : t3;
      }
      if (taken < 0) {
        rfc[0] = (selfc && kk1 == 0) ? r : rfc[0];
        rfc[1] = (selfc && kk1 == 1) ? r : rfc[1];
        rfc[2] = (selfc && kk1 == 2) ? r : rfc[2];
        rfc[3] = (selfc && kk1 == 3) ? r : rfc[3];
        if (lane == r) c4r = j1;
      }
    }
  }
  u64 free_mask = __ballot((lane < L) && (c4r < 0));

  // Key payload per owned column: (j << 7) | (row4col[j] + 1).
  int ba[4];
#pragma unroll
  for (int k = 0; k < 4; ++k) ba[k] = ((lane + 64 * k) << 7) | (rfc[k] + 1);

  const double INF = (double)INFINITY;

  // ---- SSP for free rows (exact, register-resident) ----
  while (free_mask) {
    const int cur_row = (int)__builtin_ctzll(free_mask);
    free_mask &= free_mask - 1;

    double shk[4] = {INF, INF, INF, INF};
    int pv[4] = {0, 0, 0, 0};
    int schi[4] = {0, 0, 0, 0};
    double mv_join = 0.0;
    int joined = 0;
    double min_val = 0.0;
    int i_cur = cur_row;
    double u_i = readlane_f64(u_reg, i_cur);
    float lx = readlane_f32(labx, i_cur);
    float ly = readlane_f32(laby, i_cur);
    float lz = readlane_f32(labz, i_cur);
    double t = 0.0 - u_i;
    int sink = -1;

    while (true) {
      double tv[4];
#pragma unroll
      for (int k = 0; k < 4; ++k) tv[k] = t - v[k];

      double cand[4];
#pragma unroll
      for (int k = 0; k < 4; ++k) {
        const float cf = costf(px[k], py[k], pz[k], lc[k], lca[k], lx, ly, lz);
        double dd = (double)cf + tv[k];
        dd = fmax(dd, 0.0);  // keys stay >= 0
        const int klo = (lo32d(dd) & ~PAYBITS) | ba[k];
        const int khi = hi32d(dd);
        const int khi_m = schi[k] ? 0x7FEFFFFF : khi;  // huge-finite SC mask
        const double ckey = mkdbl(klo, khi_m);
        const bool upd = ckey < shk[k];
        shk[k] = upd ? ckey : shk[k];
        pv[k]  = upd ? i_cur : pv[k];
        cand[k] = ckey;
      }
      const double m01 = fmin(cand[0], cand[1]);
      const double m23 = fmin(cand[2], cand[3]);
      double ck = fmin(m01, m23);
      DPP_MIN_F64(0x111, 0xF);  // row_shr:1
      DPP_MIN_F64(0x112, 0xF);  // row_shr:2
      DPP_MIN_F64(0x114, 0xF);  // row_shr:4
      DPP_MIN_F64(0x118, 0xF);  // row_shr:8
      DPP_MIN_F64(0x142, 0xA);  // row_bcast:15 -> rows 1,3
      DPP_MIN_F64(0x143, 0xC);  // row_bcast:31 -> rows 2,3
      const int wlo = __builtin_amdgcn_readlane(lo32d(ck), 63);
      const int whi = __builtin_amdgcn_readlane(hi32d(ck), 63);
      const int j_min = (wlo >> 7) & 0xFF;
      const int r4 = (wlo & 0x7F) - 1;   // row4col[j_min], from the key
      min_val = mkdbl(wlo & ~PAYBITS, whi);
      const int kk = j_min >> 6;
      const int hit = (lane == (j_min & 63)) ? 1 : 0;
      schi[0] |= hit & (int)(kk == 0);
      schi[1] |= hit & (int)(kk == 1);
      schi[2] |= hit & (int)(kk == 2);
      schi[3] |= hit & (int)(kk == 3);
      if (r4 < 0) { sink = j_min; break; }
      i_cur = r4;
      if (lane == i_cur) { mv_join = min_val; joined = 1; }
      u_i = readlane_f64(u_reg, i_cur);
      lx = readlane_f32(labx, i_cur);
      ly = readlane_f32(laby, i_cur);
      lz = readlane_f32(labz, i_cur);
      t = min_val - u_i;
    }

    if (lane == cur_row)  u_reg += min_val;
    else if (joined)      u_reg += min_val - mv_join;
#pragma unroll
    for (int k = 0; k < 4; ++k) {
      if (schi[k]) {
        const double shd = mkdbl(lo32d(shk[k]) & ~PAYBITS, hi32d(shk[k]));
        v[k] -= (min_val - shd);
      }
    }

    // Augment: lockstep walk over registers.
    {
      int j = sink;
      while (true) {
        const int kkj = j >> 6, lj = j & 63;
        const int p0 = __builtin_amdgcn_readlane(pv[0], lj);
        const int p1 = __builtin_amdgcn_readlane(pv[1], lj);
        const int p2 = __builtin_amdgcn_readlane(pv[2], lj);
        const int p3 = __builtin_amdgcn_readlane(pv[3], lj);
        const int ii = (kkj == 0) ? p0 : (kkj == 1) ? p1 : (kkj == 2) ? p2 : p3;
        const bool self = (lane == lj);
        rfc[0] = (self && kkj == 0) ? ii : rfc[0];
        rfc[1] = (self && kkj == 1) ? ii : rfc[1];
        rfc[2] = (self && kkj == 2) ? ii : rfc[2];
        rfc[3] = (self && kkj == 3) ? ii : rfc[3];
        const int jn = __builtin_amdgcn_readlane(c4r, ii);
        if (lane == ii) c4r = j;
        if (ii == cur_row) break;
        j = jn;
      }
    }
    // Refresh key payloads with the new row4col.
#pragma unroll
    for (int k = 0; k < 4; ++k) ba[k] = ((lane + 64 * k) << 7) | (rfc[k] + 1);
  }

  // ---- Loss partials ----
  double loc = 0.0, cpos = 0.0, cneg = 0.0;
#pragma unroll
  for (int k = 0; k < 4; ++k) {
    const int l = rfc[k];
    if (l >= 0) {
      const float d0 = __fsub_rn(px[k], lab_x[l]);
      const float d1 = __fsub_rn(py[k], lab_y[l]);
      const float d2 = __fsub_rn(pz[k], lab_z[l]);
      const float nd = __fadd_rn(__fadd_rn(__fmul_rn(d0, d0), __fmul_rn(d1, d1)),
                                 __fmul_rn(d2, d2));
      loc += (double)nd;
      cpos -= (double)lc[k];
    } else {
      cneg -= (double)lca[k];
    }
  }
  for (int off = 32; off >= 1; off >>= 1) {
    loc += __shfl_xor(loc, off, 64);
    cpos += __shfl_xor(cpos, off, 64);
    cneg += __shfl_xor(cneg, off, 64);
  }

  // ---- Fused finalization via device-scope atomics + ticket counter ----
  if (lane == 0) {
    atomicAdd(&ws[0], loc);
    atomicAdd(&ws[1], cpos + cneg + 1e-4);
    if (b == B_ - 1) { atomicAdd(&ws[2], cpos); atomicAdd(&ws[3], cneg); }
    __threadfence();
    unsigned int* cnt = (unsigned int*)(ws + 4);
    const unsigned int old = atomicAdd(cnt, 1u);
    if (old == (unsigned int)(B_ - 1)) {
      __threadfence();
      const double loc_t  = atomicAdd(&ws[0], 0.0);
      const double conf_t = atomicAdd(&ws[1], 0.0);
      const double cpos_l = atomicAdd(&ws[2], 0.0);
      const double cneg_l = atomicAdd(&ws[3], 0.0);
      const double lloc = 0.1 * (loc_t * 0.5);  // ALPHA * location_loss
      out[0] = (float)(lloc + conf_t);
      out[1] = (float)lloc;
      out[2] = (float)cpos_l;
      out[3] = (float)cneg_l;
    }
  }
}

extern "C" void kernel_launch(void* const* d_in, const int* in_sizes, int n_in,
                              void* d_out, int out_size, void* d_ws, size_t ws_size,
                              hipStream_t stream) {
  const float* pred = (const float*)d_in[0];       // (B, N, 4) fp32
  const float* label = (const float*)d_in[1];      // (B, M, 3) fp32
  const int* label_len = (const int*)d_in[2];      // (B,) int32
  double* ws = (double*)d_ws;
  float* out = (float*)d_out;

  hipMemsetAsync(d_ws, 0, 64, stream);  // 4 f64 accumulators + ticket
  lsa_loss_kernel<<<B_, 64, 0, stream>>>(pred, label, label_len, ws, out);
}

// Round 9
// 185.387 us; speedup vs baseline: 1.3557x; 1.1144x over previous
//
#include <hip/hip_runtime.h>
#include <math.h>

// LineFinderLoss: B=384 independent exact LSAs (L x 256, L<=64) + loss.
// One wave per batch; each lane owns 4 pred columns (j = lane + 64k).
// Round 9: INTEGER JV. Costs quantized to fixed-point 2^15:
//   Q_ij = trunc(0.05*nd*2^15) + trunc((lca-lc)*2^15)
// and the whole Dijkstra runs in exact int32 (rc>=0 invariant exact, no fp
// guards). Key = (d << 8) | j  (j = 64k+lane, so u32 order == (d, j) order
// with numpy's first-j tie-break). Wave argmin = v_min_u32 DPP chain
// (VOP2, DPP-fusable) — ~2x cheaper than the R8 f64 chain. SC columns are
// retired by biasing qg[k] += 0x30000000 at pop time (off critical path);
// d is clamped to 0x7FFFFE so packing stays sign-safe.
// Solution = exact optimum of a matrix within 6e-5 of the reference's C;
// epilogue computes the loss with exact reference fp arithmetic.

#define B_ 384
#define N_ 256
#define M_ 64

typedef unsigned long long u64;
typedef unsigned int u32;

#define WOFF   (1 << 20)       // warm-start key offset (Q can be negative)
#define SCBIAS 0x30000000      // qg bias retiring an SC column
#define DCLAMP 0x007FFFFE      // d clamp: (DCLAMP<<8)|255 < INT_MAX

static __device__ __forceinline__ float readlane_f32(float x, int l) {
  return __int_as_float(__builtin_amdgcn_readlane(__float_as_int(x), l));
}

// Quantizer geometric term — identical instruction sequence at every call
// site (explicit _rn intrinsics, no contraction ambiguity), so Q_ij is a
// consistent function of (i, j).
static __device__ __forceinline__ int qsf(float px, float py, float pz,
                                          float lx, float ly, float lz) {
  const float d0 = __fsub_rn(px, lx);
  const float d1 = __fsub_rn(py, ly);
  const float d2 = __fsub_rn(pz, lz);
  const float nd = __fmaf_rn(d2, d2, __fmaf_rn(d1, d1, __fmul_rn(d0, d0)));
  return (int)__fmul_rn(nd, 1638.4f);   // 0.05 * 2^15
}

// u32 min-reduce step via DPP; lanes without a source contribute INT_MAX.
#define DPP_MIN_U32(CTRL, RMASK)                                               \
  {                                                                            \
    u32 nk = (u32)__builtin_amdgcn_update_dpp(0x7FFFFFFF, (int)ck,             \
                                              CTRL, RMASK, 0xF, false);        \
    ck = (nk < ck) ? nk : ck;                                                  \
  }

#define WAVE_MIN_U32()                                                         \
  DPP_MIN_U32(0x111, 0xF);  /* row_shr:1  */                                   \
  DPP_MIN_U32(0x112, 0xF);  /* row_shr:2  */                                   \
  DPP_MIN_U32(0x114, 0xF);  /* row_shr:4  */                                   \
  DPP_MIN_U32(0x118, 0xF);  /* row_shr:8  */                                   \
  DPP_MIN_U32(0x142, 0xA);  /* row_bcast:15 -> rows 1,3 */                     \
  DPP_MIN_U32(0x143, 0xC);  /* row_bcast:31 -> rows 2,3 */

__global__ __launch_bounds__(64) void lsa_loss_kernel(
    const float* __restrict__ pred,
    const float* __restrict__ label,
    const int* __restrict__ label_len,
    double* __restrict__ ws,
    float* __restrict__ out)
{
  const int b = blockIdx.x;
  const int lane = threadIdx.x;  // 0..63

  __shared__ float lab_x[M_], lab_y[M_], lab_z[M_];

  const float* lp = label + (size_t)(b * M_ + lane) * 3;
  const float labx = lp[0], laby = lp[1], labz = lp[2];
  lab_x[lane] = labx; lab_y[lane] = laby; lab_z[lane] = labz;

  float px[4], py[4], pz[4], lc[4], lca[4];
  int qg[4];   // trunc((lca-lc)*2^15); +SCBIAS while the column is in SC
  int v[4];    // column duals (int32)
  const float4* pred4 = reinterpret_cast<const float4*>(pred);
#pragma unroll
  for (int k = 0; k < 4; ++k) {
    const float4 p = pred4[b * N_ + lane + 64 * k];
    px[k] = p.x; py[k] = p.y; pz[k] = p.z;
    lc[k]  = logf(__fadd_rn(p.w, 1e-5f));
    lca[k] = logf(__fadd_rn(__fsub_rn(1.0f, p.w), 1e-5f));
    qg[k] = (int)__fmul_rn(__fsub_rn(lca[k], lc[k]), 32768.0f);
    v[k] = 0;
  }
  int rfc[4] = {-1, -1, -1, -1};  // row4col, distributed (col j=lane+64k)
  int c4r = -1;                   // col4row[lane]
  int u_reg = 0;                  // u[lane] (int32)

  int L = label_len[b];
  L = (L < 1) ? 1 : ((L > M_) ? M_ : L);

  __syncthreads();  // labels visible (epilogue gather)

  // ---- Warm start: u_i = min_j Q_ij (exact int row reduction), v = 0,
  //      greedy claim of each row's argmin column (tight edges). ----
  for (int r = 0; r < L; ++r) {
    const float lx = readlane_f32(labx, r);
    const float ly = readlane_f32(laby, r);
    const float lz = readlane_f32(labz, r);
    u32 cand[4];
#pragma unroll
    for (int k = 0; k < 4; ++k) {
      const int j = lane + 64 * k;
      const int q = qsf(px[k], py[k], pz[k], lx, ly, lz) + qg[k];
      cand[k] = ((u32)(q + WOFF) << 8) | (u32)j;
    }
    const u32 m01 = (cand[0] < cand[1]) ? cand[0] : cand[1];
    const u32 m23 = (cand[2] < cand[3]) ? cand[2] : cand[3];
    u32 ck = (m01 < m23) ? m01 : m23;
    WAVE_MIN_U32();
    const u32 wk = (u32)__builtin_amdgcn_readlane((int)ck, 63);
    const int j1 = (int)(wk & 0xFF);
    if (lane == r) u_reg = (int)(wk >> 8) - WOFF;
    const int kk1 = j1 >> 6;
    const int lsel = j1 & 63;
    const int t0 = __builtin_amdgcn_readlane(rfc[0], lsel);
    const int t1 = __builtin_amdgcn_readlane(rfc[1], lsel);
    const int t2 = __builtin_amdgcn_readlane(rfc[2], lsel);
    const int t3 = __builtin_amdgcn_readlane(rfc[3], lsel);
    const int taken = (kk1 == 0) ? t0 : (kk1 == 1) ? t1 : (kk1 == 2) ? t2 : t3;
    if (taken < 0) {
      const bool selfc = (lane == lsel);
      rfc[0] = (selfc && kk1 == 0) ? r : rfc[0];
      rfc[1] = (selfc && kk1 == 1) ? r : rfc[1];
      rfc[2] = (selfc && kk1 == 2) ? r : rfc[2];
      rfc[3] = (selfc && kk1 == 3) ? r : rfc[3];
      if (lane == r) c4r = j1;
    }
  }
  u64 free_mask = __ballot((lane < L) && (c4r < 0));

  // ---- SSP for free rows (exact integer shortest augmenting path) ----
  while (free_mask) {
    const int cur_row = (int)__builtin_ctzll(free_mask);
    free_mask &= free_mask - 1;

    u32 shk[4] = {0x7FFFFFFFu, 0x7FFFFFFFu, 0x7FFFFFFFu, 0x7FFFFFFFu};
    int pv[4] = {0, 0, 0, 0};
    int schi[4] = {0, 0, 0, 0};
    int mv_join = 0;
    int joined = 0;
    int min_val = 0;
    int i_cur = cur_row;
    int u_i = __builtin_amdgcn_readlane(u_reg, i_cur);
    float lx = readlane_f32(labx, i_cur);
    float ly = readlane_f32(laby, i_cur);
    float lz = readlane_f32(labz, i_cur);
    int t = 0 - u_i;  // t = min_val - u_i
    int sink = -1;

    while (true) {
      int tvg[4];
#pragma unroll
      for (int k = 0; k < 4; ++k) tvg[k] = (t - v[k]) + qg[k];

      u32 cand[4];
#pragma unroll
      for (int k = 0; k < 4; ++k) {
        const int j = lane + 64 * k;
        int dd = qsf(px[k], py[k], pz[k], lx, ly, lz) + tvg[k];
        dd = (dd < DCLAMP) ? dd : DCLAMP;           // sign-safe packing
        const u32 key = ((u32)dd << 8) | (u32)j;    // SC'd: qg bias -> huge
        const bool upd = key < shk[k];
        shk[k] = upd ? key : shk[k];
        pv[k]  = upd ? i_cur : pv[k];
        cand[k] = key;
      }
      const u32 m01 = (cand[0] < cand[1]) ? cand[0] : cand[1];
      const u32 m23 = (cand[2] < cand[3]) ? cand[2] : cand[3];
      u32 ck = (m01 < m23) ? m01 : m23;
      WAVE_MIN_U32();
      const u32 wk = (u32)__builtin_amdgcn_readlane((int)ck, 63);
      const int j_min = (int)(wk & 0xFF);
      min_val = (int)(wk >> 8);
      const int kk = j_min >> 6;
      const int lsel = j_min & 63;
      const bool selfc = (lane == lsel);
      // Retire the popped column (off critical path): SC flag + qg bias.
      schi[0] |= (selfc && kk == 0) ? 1 : 0;
      schi[1] |= (selfc && kk == 1) ? 1 : 0;
      schi[2] |= (selfc && kk == 2) ? 1 : 0;
      schi[3] |= (selfc && kk == 3) ? 1 : 0;
      qg[0] += (selfc && kk == 0) ? SCBIAS : 0;
      qg[1] += (selfc && kk == 1) ? SCBIAS : 0;
      qg[2] += (selfc && kk == 2) ? SCBIAS : 0;
      qg[3] += (selfc && kk == 3) ? SCBIAS : 0;
      // row4col[j_min] from distributed registers.
      const int r0 = __builtin_amdgcn_readlane(rfc[0], lsel);
      const int r1 = __builtin_amdgcn_readlane(rfc[1], lsel);
      const int r2 = __builtin_amdgcn_readlane(rfc[2], lsel);
      const int r3 = __builtin_amdgcn_readlane(rfc[3], lsel);
      const int r4 = (kk == 0) ? r0 : (kk == 1) ? r1 : (kk == 2) ? r2 : r3;
      if (r4 < 0) { sink = j_min; break; }
      i_cur = r4;
      if (lane == i_cur) { mv_join = min_val; joined = 1; }
      u_i = __builtin_amdgcn_readlane(u_reg, i_cur);
      lx = readlane_f32(labx, i_cur);
      ly = readlane_f32(laby, i_cur);
      lz = readlane_f32(labz, i_cur);
      t = min_val - u_i;
    }

    // Dual updates (exact int, pre-augmentation matching).
    if (lane == cur_row)  u_reg += min_val;
    else if (joined)      u_reg += min_val - mv_join;
#pragma unroll
    for (int k = 0; k < 4; ++k) {
      if (schi[k]) {
        v[k] -= (min_val - (int)(shk[k] >> 8));
        qg[k] -= SCBIAS;  // restore for the next Dijkstra
      }
    }

    // Augment: lockstep walk over registers.
    {
      int j = sink;
      while (true) {
        const int kkj = j >> 6, lj = j & 63;
        const int p0 = __builtin_amdgcn_readlane(pv[0], lj);
        const int p1 = __builtin_amdgcn_readlane(pv[1], lj);
        const int p2 = __builtin_amdgcn_readlane(pv[2], lj);
        const int p3 = __builtin_amdgcn_readlane(pv[3], lj);
        const int ii = (kkj == 0) ? p0 : (kkj == 1) ? p1 : (kkj == 2) ? p2 : p3;
        const bool self = (lane == lj);
        rfc[0] = (self && kkj == 0) ? ii : rfc[0];
        rfc[1] = (self && kkj == 1) ? ii : rfc[1];
        rfc[2] = (self && kkj == 2) ? ii : rfc[2];
        rfc[3] = (self && kkj == 3) ? ii : rfc[3];
        const int jn = __builtin_amdgcn_readlane(c4r, ii);
        if (lane == ii) c4r = j;
        if (ii == cur_row) break;
        j = jn;
      }
    }
  }

  // ---- Loss partials: exact reference fp arithmetic on the assignment ----
  double loc = 0.0, cpos = 0.0, cneg = 0.0;
#pragma unroll
  for (int k = 0; k < 4; ++k) {
    const int l = rfc[k];
    if (l >= 0) {
      const float d0 = __fsub_rn(px[k], lab_x[l]);
      const float d1 = __fsub_rn(py[k], lab_y[l]);
      const float d2 = __fsub_rn(pz[k], lab_z[l]);
      const float nd = __fadd_rn(__fadd_rn(__fmul_rn(d0, d0), __fmul_rn(d1, d1)),
                                 __fmul_rn(d2, d2));
      loc += (double)nd;
      cpos -= (double)lc[k];
    } else {
      cneg -= (double)lca[k];
    }
  }
  for (int off = 32; off >= 1; off >>= 1) {
    loc += __shfl_xor(loc, off, 64);
    cpos += __shfl_xor(cpos, off, 64);
    cneg += __shfl_xor(cneg, off, 64);
  }

  // ---- Fused finalization via device-scope atomics + ticket counter ----
  if (lane == 0) {
    atomicAdd(&ws[0], loc);
    atomicAdd(&ws[1], cpos + cneg + 1e-4);
    if (b == B_ - 1) { atomicAdd(&ws[2], cpos); atomicAdd(&ws[3], cneg); }
    __threadfence();
    unsigned int* cnt = (unsigned int*)(ws + 4);
    const unsigned int old = atomicAdd(cnt, 1u);
    if (old == (unsigned int)(B_ - 1)) {
      __threadfence();
      const double loc_t  = atomicAdd(&ws[0], 0.0);
      const double conf_t = atomicAdd(&ws[1], 0.0);
      const double cpos_l = atomicAdd(&ws[2], 0.0);
      const double cneg_l = atomicAdd(&ws[3], 0.0);
      const double lloc = 0.1 * (loc_t * 0.5);  // ALPHA * location_loss
      out[0] = (float)(lloc + conf_t);
      out[1] = (float)lloc;
      out[2] = (float)cpos_l;
      out[3] = (float)cneg_l;
    }
  }
}

extern "C" void kernel_launch(void* const* d_in, const int* in_sizes, int n_in,
                              void* d_out, int out_size, void* d_ws, size_t ws_size,
                              hipStream_t stream) {
  const float* pred = (const float*)d_in[0];       // (B, N, 4) fp32
  const float* label = (const float*)d_in[1];      // (B, M, 3) fp32
  const int* label_len = (const int*)d_in[2];      // (B,) int32
  double* ws = (double*)d_ws;
  float* out = (float*)d_out;

  hipMemsetAsync(d_ws, 0, 64, stream);  // 4 f64 accumulators + ticket
  lsa_loss_kernel<<<B_, 64, 0, stream>>>(pred, label, label_len, ws, out);
}

// Round 10
// 171.662 us; speedup vs baseline: 1.4641x; 1.0800x over previous
//
#include <hip/hip_runtime.h>
#include <math.h>

// LineFinderLoss: B=384 independent exact LSAs (L x 256, L<=64) + loss.
// One wave per batch; each lane owns 4 pred columns (j = lane + 64k).
// Round 10: integer JV (R9) with two critical-path cuts:
//  - wave argmin = fused v_min_u32_dpp chain (inline asm, 1 inst/step,
//    s_nop 1 guards for the VALU->DPP-src hazard invisible inside asm).
//  - cost in dot form: Q_ij = trunc(fma(dot(p_j, l_i), -3276.8, base_j)),
//    base_j = 1638.4*|p_j|^2 + 32768*(lca-lc) precomputed per lane.
//    The per-row |l_i|^2 term is dropped: row-constant (+-1 after trunc)
//    offsets never change the optimal assignment (all L rows matched).
// Key = (d << 8) | j keeps numpy's first-j tie-break; SC columns retired
// by scb[k] += SCBIAS at pop (clamped to DCLAMP, sign-safe packing).
// Epilogue computes the loss with exact reference fp arithmetic.

#define B_ 384
#define N_ 256
#define M_ 64

typedef unsigned long long u64;
typedef unsigned int u32;

#define WOFF   (1 << 20)       // warm-start key offset (Q can be negative)
#define SCBIAS 0x30000000      // scb bias retiring an SC column
#define DCLAMP 0x007FFFFE      // d clamp: (DCLAMP<<8)|255 < INT_MAX

static __device__ __forceinline__ float readlane_f32(float x, int l) {
  return __int_as_float(__builtin_amdgcn_readlane(__float_as_int(x), l));
}

// Quantized cost (consistent: same instruction sequence at every call site).
static __device__ __forceinline__ int qcost(float px_, float py_, float pz_,
                                            float base_,
                                            float lx, float ly, float lz) {
  const float t1 = __fmul_rn(px_, lx);
  const float t2 = __fmaf_rn(py_, ly, t1);
  const float t3 = __fmaf_rn(pz_, lz, t2);
  return (int)__fmaf_rn(t3, -3276.8f, base_);   // -2 * 0.05 * 2^15
}

// Wave-min over 64 lanes into lane 63: fused VOP2-DPP v_min_u32 chain.
// bound_ctrl omitted (=0): invalid-source lanes keep their value (identity
// merge). s_nop 1 covers the gfx9 VALU-write -> DPP-read hazard.
static __device__ __forceinline__ u32 wave_min_u32(u32 ck) {
  asm("s_nop 1\n\t"
      "v_min_u32_dpp %0, %0, %0 row_shr:1 row_mask:0xf bank_mask:0xf\n\t"
      "s_nop 1\n\t"
      "v_min_u32_dpp %0, %0, %0 row_shr:2 row_mask:0xf bank_mask:0xf\n\t"
      "s_nop 1\n\t"
      "v_min_u32_dpp %0, %0, %0 row_shr:4 row_mask:0xf bank_mask:0xf\n\t"
      "s_nop 1\n\t"
      "v_min_u32_dpp %0, %0, %0 row_shr:8 row_mask:0xf bank_mask:0xf\n\t"
      "s_nop 1\n\t"
      "v_min_u32_dpp %0, %0, %0 row_bcast:15 row_mask:0xa bank_mask:0xf\n\t"
      "s_nop 1\n\t"
      "v_min_u32_dpp %0, %0, %0 row_bcast:31 row_mask:0xc bank_mask:0xf"
      : "+v"(ck));
  return ck;
}

__global__ __launch_bounds__(64) void lsa_loss_kernel(
    const float* __restrict__ pred,
    const float* __restrict__ label,
    const int* __restrict__ label_len,
    double* __restrict__ ws,
    float* __restrict__ out)
{
  const int b = blockIdx.x;
  const int lane = threadIdx.x;  // 0..63

  __shared__ float lab_x[M_], lab_y[M_], lab_z[M_];

  const float* lp = label + (size_t)(b * M_ + lane) * 3;
  const float labx = lp[0], laby = lp[1], labz = lp[2];
  lab_x[lane] = labx; lab_y[lane] = laby; lab_z[lane] = labz;

  float px[4], py[4], pz[4], lc[4], lca[4], base[4];
  int v[4];    // column duals (int32)
  int scb[4];  // 0, or SCBIAS while the column is in SC
  const float4* pred4 = reinterpret_cast<const float4*>(pred);
#pragma unroll
  for (int k = 0; k < 4; ++k) {
    const float4 p = pred4[b * N_ + lane + 64 * k];
    px[k] = p.x; py[k] = p.y; pz[k] = p.z;
    lc[k]  = logf(__fadd_rn(p.w, 1e-5f));
    lca[k] = logf(__fadd_rn(__fsub_rn(1.0f, p.w), 1e-5f));
    const float qgf = __fmul_rn(__fsub_rn(lca[k], lc[k]), 32768.0f);
    const float npp = __fmaf_rn(p.z, p.z, __fmaf_rn(p.y, p.y, __fmul_rn(p.x, p.x)));
    base[k] = __fmaf_rn(npp, 1638.4f, qgf);
    v[k] = 0;
    scb[k] = 0;
  }
  int rfc[4] = {-1, -1, -1, -1};  // row4col, distributed (col j=lane+64k)
  int c4r = -1;                   // col4row[lane]
  int u_reg = 0;                  // u[lane] (int32)

  int L = label_len[b];
  L = (L < 1) ? 1 : ((L > M_) ? M_ : L);

  __syncthreads();  // labels visible (epilogue gather)

  // ---- Warm start: u_i = min_j Q_ij (exact int row reduction), v = 0,
  //      greedy claim of each row's argmin column (tight edges). ----
  for (int r = 0; r < L; ++r) {
    const float lx = readlane_f32(labx, r);
    const float ly = readlane_f32(laby, r);
    const float lz = readlane_f32(labz, r);
    u32 cand[4];
#pragma unroll
    for (int k = 0; k < 4; ++k) {
      const int j = lane + 64 * k;
      const int q = qcost(px[k], py[k], pz[k], base[k], lx, ly, lz);
      cand[k] = ((u32)(q + WOFF) << 8) | (u32)j;
    }
    const u32 m01 = (cand[0] < cand[1]) ? cand[0] : cand[1];
    const u32 m23 = (cand[2] < cand[3]) ? cand[2] : cand[3];
    u32 ck = wave_min_u32((m01 < m23) ? m01 : m23);
    const u32 wk = (u32)__builtin_amdgcn_readlane((int)ck, 63);
    const int j1 = (int)(wk & 0xFF);
    if (lane == r) u_reg = (int)(wk >> 8) - WOFF;
    const int kk1 = j1 >> 6;
    const int lsel = j1 & 63;
    const int t0 = __builtin_amdgcn_readlane(rfc[0], lsel);
    const int t1 = __builtin_amdgcn_readlane(rfc[1], lsel);
    const int t2 = __builtin_amdgcn_readlane(rfc[2], lsel);
    const int t3 = __builtin_amdgcn_readlane(rfc[3], lsel);
    const int taken = (kk1 == 0) ? t0 : (kk1 == 1) ? t1 : (kk1 == 2) ? t2 : t3;
    if (taken < 0) {
      const bool selfc = (lane == lsel);
      rfc[0] = (selfc && kk1 == 0) ? r : rfc[0];
      rfc[1] = (selfc && kk1 == 1) ? r : rfc[1];
      rfc[2] = (selfc && kk1 == 2) ? r : rfc[2];
      rfc[3] = (selfc && kk1 == 3) ? r : rfc[3];
      if (lane == r) c4r = j1;
    }
  }
  u64 free_mask = __ballot((lane < L) && (c4r < 0));

  // ---- SSP for free rows (exact integer shortest augmenting path) ----
  while (free_mask) {
    const int cur_row = (int)__builtin_ctzll(free_mask);
    free_mask &= free_mask - 1;

    u32 shk[4] = {0x7FFFFFFFu, 0x7FFFFFFFu, 0x7FFFFFFFu, 0x7FFFFFFFu};
    int pv[4] = {0, 0, 0, 0};
    int mv_join = 0;
    int joined = 0;
    int min_val = 0;
    int i_cur = cur_row;
    int u_i = __builtin_amdgcn_readlane(u_reg, i_cur);
    float lx = readlane_f32(labx, i_cur);
    float ly = readlane_f32(laby, i_cur);
    float lz = readlane_f32(labz, i_cur);
    int t = 0 - u_i;  // t = min_val - u_i
    int sink = -1;

    while (true) {
      int tv[4];
#pragma unroll
      for (int k = 0; k < 4; ++k) tv[k] = (t - v[k]) + scb[k];

      u32 cand[4];
#pragma unroll
      for (int k = 0; k < 4; ++k) {
        const int j = lane + 64 * k;
        int dd = qcost(px[k], py[k], pz[k], base[k], lx, ly, lz) + tv[k];
        dd = (dd < DCLAMP) ? dd : DCLAMP;           // sign-safe packing
        const u32 key = ((u32)dd << 8) | (u32)j;    // SC'd: scb bias -> huge
        const bool upd = key < shk[k];
        shk[k] = upd ? key : shk[k];
        pv[k]  = upd ? i_cur : pv[k];
        cand[k] = key;
      }
      const u32 m01 = (cand[0] < cand[1]) ? cand[0] : cand[1];
      const u32 m23 = (cand[2] < cand[3]) ? cand[2] : cand[3];
      u32 ck = wave_min_u32((m01 < m23) ? m01 : m23);
      const u32 wk = (u32)__builtin_amdgcn_readlane((int)ck, 63);
      const int j_min = (int)(wk & 0xFF);
      min_val = (int)(wk >> 8);
      const int kk = j_min >> 6;
      const int lsel = j_min & 63;
      const bool selfc = (lane == lsel);
      // Retire the popped column (off critical path): scb bias.
      scb[0] += (selfc && kk == 0) ? SCBIAS : 0;
      scb[1] += (selfc && kk == 1) ? SCBIAS : 0;
      scb[2] += (selfc && kk == 2) ? SCBIAS : 0;
      scb[3] += (selfc && kk == 3) ? SCBIAS : 0;
      // row4col[j_min] from distributed registers.
      const int r0 = __builtin_amdgcn_readlane(rfc[0], lsel);
      const int r1 = __builtin_amdgcn_readlane(rfc[1], lsel);
      const int r2 = __builtin_amdgcn_readlane(rfc[2], lsel);
      const int r3 = __builtin_amdgcn_readlane(rfc[3], lsel);
      const int r4 = (kk == 0) ? r0 : (kk == 1) ? r1 : (kk == 2) ? r2 : r3;
      if (r4 < 0) { sink = j_min; break; }
      i_cur = r4;
      if (lane == i_cur) { mv_join = min_val; joined = 1; }
      u_i = __builtin_amdgcn_readlane(u_reg, i_cur);
      lx = readlane_f32(labx, i_cur);
      ly = readlane_f32(laby, i_cur);
      lz = readlane_f32(labz, i_cur);
      t = min_val - u_i;
    }

    // Dual updates (exact int, pre-augmentation matching).
    if (lane == cur_row)  u_reg += min_val;
    else if (joined)      u_reg += min_val - mv_join;
#pragma unroll
    for (int k = 0; k < 4; ++k) {
      if (scb[k]) {
        v[k] -= (min_val - (int)(shk[k] >> 8));
        scb[k] = 0;  // restore for the next Dijkstra
      }
    }

    // Augment: lockstep walk over registers.
    {
      int j = sink;
      while (true) {
        const int kkj = j >> 6, lj = j & 63;
        const int p0 = __builtin_amdgcn_readlane(pv[0], lj);
        const int p1 = __builtin_amdgcn_readlane(pv[1], lj);
        const int p2 = __builtin_amdgcn_readlane(pv[2], lj);
        const int p3 = __builtin_amdgcn_readlane(pv[3], lj);
        const int ii = (kkj == 0) ? p0 : (kkj == 1) ? p1 : (kkj == 2) ? p2 : p3;
        const bool self = (lane == lj);
        rfc[0] = (self && kkj == 0) ? ii : rfc[0];
        rfc[1] = (self && kkj == 1) ? ii : rfc[1];
        rfc[2] = (self && kkj == 2) ? ii : rfc[2];
        rfc[3] = (self && kkj == 3) ? ii : rfc[3];
        const int jn = __builtin_amdgcn_readlane(c4r, ii);
        if (lane == ii) c4r = j;
        if (ii == cur_row) break;
        j = jn;
      }
    }
  }

  // ---- Loss partials: exact reference fp arithmetic on the assignment ----
  double loc = 0.0, cpos = 0.0, cneg = 0.0;
#pragma unroll
  for (int k = 0; k < 4; ++k) {
    const int l = rfc[k];
    if (l >= 0) {
      const float d0 = __fsub_rn(px[k], lab_x[l]);
      const float d1 = __fsub_rn(py[k], lab_y[l]);
      const float d2 = __fsub_rn(pz[k], lab_z[l]);
      const float nd = __fadd_rn(__fadd_rn(__fmul_rn(d0, d0), __fmul_rn(d1, d1)),
                                 __fmul_rn(d2, d2));
      loc += (double)nd;
      cpos -= (double)lc[k];
    } else {
      cneg -= (double)lca[k];
    }
  }
  for (int off = 32; off >= 1; off >>= 1) {
    loc += __shfl_xor(loc, off, 64);
    cpos += __shfl_xor(cpos, off, 64);
    cneg += __shfl_xor(cneg, off, 64);
  }

  // ---- Fused finalization via device-scope atomics + ticket counter ----
  if (lane == 0) {
    atomicAdd(&ws[0], loc);
    atomicAdd(&ws[1], cpos + cneg + 1e-4);
    if (b == B_ - 1) { atomicAdd(&ws[2], cpos); atomicAdd(&ws[3], cneg); }
    __threadfence();
    unsigned int* cnt = (unsigned int*)(ws + 4);
    const unsigned int old = atomicAdd(cnt, 1u);
    if (old == (unsigned int)(B_ - 1)) {
      __threadfence();
      const double loc_t  = atomicAdd(&ws[0], 0.0);
      const double conf_t = atomicAdd(&ws[1], 0.0);
      const double cpos_l = atomicAdd(&ws[2], 0.0);
      const double cneg_l = atomicAdd(&ws[3], 0.0);
      const double lloc = 0.1 * (loc_t * 0.5);  // ALPHA * location_loss
      out[0] = (float)(lloc + conf_t);
      out[1] = (float)lloc;
      out[2] = (float)cpos_l;
      out[3] = (float)cneg_l;
    }
  }
}

extern "C" void kernel_launch(void* const* d_in, const int* in_sizes, int n_in,
                              void* d_out, int out_size, void* d_ws, size_t ws_size,
                              hipStream_t stream) {
  const float* pred = (const float*)d_in[0];       // (B, N, 4) fp32
  const float* label = (const float*)d_in[1];      // (B, M, 3) fp32
  const int* label_len = (const int*)d_in[2];      // (B,) int32
  double* ws = (double*)d_ws;
  float* out = (float*)d_out;

  hipMemsetAsync(d_ws, 0, 64, stream);  // 4 f64 accumulators + ticket
  lsa_loss_kernel<<<B_, 64, 0, stream>>>(pred, label, label_len, ws, out);
}